// Round 3
// baseline (278.539 us; speedup 1.0000x reference)
//
#include <hip/hip_runtime.h>
#include <hip/hip_bf16.h>

#define DMODEL 1024
#define NHEAD  16
#define DKD    64
#define BLK    128
#define TB     16
#define SCALEF 0.125f   // TAU / sqrt(DK)

typedef __attribute__((ext_vector_type(8))) short bf16x8;
typedef __attribute__((ext_vector_type(4))) float f32x4;

#define MFMA(A, B, C) __builtin_amdgcn_mfma_f32_16x16x32_bf16(A, B, C, 0, 0, 0)

union U8 { bf16x8 v; ushort u[8]; ushort2 u2[4]; ushort4 u4[2]; };

__device__ __forceinline__ ushort2 pk2(float a, float b) {
  union { __hip_bfloat162 h; ushort2 u; } c;
  c.h = __float22bfloat162_rn(make_float2(a, b));
  return c.u;
}

// ---- LDS tile readers ----------------------------------------------------
// row tiles [R][64], XOR-swizzled by ((r&7)<<3) ushorts
__device__ __forceinline__ bf16x8 frag64(const ushort* T, int r, int c) {
  return *reinterpret_cast<const bf16x8*>(T + ((r * 64 + c) ^ ((r & 7) << 3)));
}
// [128][128] tiles (dS / PnT / dST), same swizzle
__device__ __forceinline__ bf16x8 frag128(const ushort* T, int r, int c) {
  return *reinterpret_cast<const bf16x8*>(T + ((r * 128 + c) ^ ((r & 7) << 3)));
}
// chunked transposed tile: element (d, r) at (r>>2)*256 + d*4 + (r&3); r0 % 8 == 0
__device__ __forceinline__ bf16x8 fragT2(const ushort* T, int d, int r0) {
  U8 x;
  x.u4[0] = *reinterpret_cast<const ushort4*>(T + (r0 >> 2) * 256 + d * 4);
  x.u4[1] = *reinterpret_cast<const ushort4*>(T + (r0 >> 2) * 256 + 256 + d * 4);
  return x.v;
}
// global -> register fragment (row-major source, 8 consecutive fp32)
__device__ __forceinline__ bf16x8 gfrag(const float* __restrict__ g, float sc) {
  const float4 fa = *reinterpret_cast<const float4*>(g);
  const float4 fb = *reinterpret_cast<const float4*>(g + 4);
  U8 x;
  x.u2[0] = pk2(fa.x * sc, fa.y * sc);
  x.u2[1] = pk2(fa.z * sc, fa.w * sc);
  x.u2[2] = pk2(fb.x * sc, fb.y * sc);
  x.u2[3] = pk2(fb.z * sc, fb.w * sc);
  return x.v;
}

// ---- staging -------------------------------------------------------------
// 128x64 fp32 global tile -> bf16 row tile [128][64] swizzled. 256 thr.
__device__ __forceinline__ void stage_row(ushort* T, const float* __restrict__ g,
                                          float sc, int tid) {
#pragma unroll
  for (int it = 0; it < 8; ++it) {
    const int idx = tid + 256 * it;
    const int r = idx >> 4, d4 = idx & 15;
    const float4 f = *reinterpret_cast<const float4*>(g + r * DMODEL + 4 * d4);
    const ushort2 lo = pk2(f.x * sc, f.y * sc);
    const ushort2 hi = pk2(f.z * sc, f.w * sc);
    ushort4 u; u.x = lo.x; u.y = lo.y; u.z = hi.x; u.w = hi.y;
    *reinterpret_cast<ushort4*>(T + ((r * 64 + 4 * d4) ^ ((r & 7) << 3))) = u;
  }
}

// 128x64 fp32 -> chunked transposed tile (and optionally also the row tile),
// via 4x4 shfl butterfly transpose; all LDS writes are b64, bank-balanced.
template <bool ALSO_ROW>
__device__ __forceinline__ void stage_T(ushort* T, ushort* Trow,
                                        const float* __restrict__ g, float sc, int tid) {
  const int a = (tid >> 4) & 3;
#pragma unroll
  for (int it = 0; it < 8; ++it) {
    const int idx = tid + 256 * it;
    const int r = idx >> 4, d4 = idx & 15;
    const float4 f = *reinterpret_cast<const float4*>(g + r * DMODEL + 4 * d4);
    const float w0 = f.x * sc, w1 = f.y * sc, w2 = f.z * sc, w3 = f.w * sc;
    if constexpr (ALSO_ROW) {
      const ushort2 lo = pk2(w0, w1);
      const ushort2 hi = pk2(w2, w3);
      ushort4 u; u.x = lo.x; u.y = lo.y; u.z = hi.x; u.w = hi.y;
      *reinterpret_cast<ushort4*>(Trow + ((r * 64 + 4 * d4) ^ ((r & 7) << 3))) = u;
    }
    // 4x4 transpose across lanes (lane bit4 = mask16, bit5 = mask32)
    const float s0 = __shfl_xor(w1, 16), s1 = __shfl_xor(w0, 16);
    const float s2 = __shfl_xor(w3, 16), s3 = __shfl_xor(w2, 16);
    const float u0 = (a & 1) ? s0 : w0;
    const float u1 = (a & 1) ? w1 : s1;
    const float u2 = (a & 1) ? s2 : w2;
    const float u3 = (a & 1) ? w3 : s3;
    const float t0 = __shfl_xor(u2, 32), t1 = __shfl_xor(u3, 32);
    const float t2 = __shfl_xor(u0, 32), t3 = __shfl_xor(u1, 32);
    const float z0 = (a & 2) ? t0 : u0;
    const float z1 = (a & 2) ? t1 : u1;
    const float z2 = (a & 2) ? u2 : t2;
    const float z3 = (a & 2) ? u3 : t3;
    // lane now holds rows R0..R0+3 at column d = 4*d4 + a
    const int d = 4 * d4 + a, R0 = r - a;
    const ushort2 lo = pk2(z0, z1);
    const ushort2 hi = pk2(z2, z3);
    ushort4 o; o.x = lo.x; o.y = lo.y; o.z = hi.x; o.w = hi.y;
    *reinterpret_cast<ushort4*>(T + (R0 >> 2) * 256 + d * 4) = o;
  }
}

// ---- kernel --------------------------------------------------------------
// grid 512: role(2) x h(16) x blk(16); 256 threads = 4 waves; 64 KB LDS.
// LDS map (ushort units):
//   [0,8192)      k row tile          (both roles)      } reused as
//   [8192,16384)  v row tile          (both roles)      } X = [128][128] dS/PnT/dST
//   [16384,24576) chunked T tile 0    (kT / qT)
//   [24576,32768) chunked T tile 1    (dOT, role 1)
__global__ void __launch_bounds__(256, 2)
bwd_all(const float* __restrict__ q, const float* __restrict__ kk,
        const float* __restrict__ v, const float* __restrict__ dOg,
        const int* __restrict__ mask,
        float* __restrict__ dQ, float* __restrict__ dK, float* __restrict__ dV) {
  __shared__ ushort sm[32768];
  ushort* smK = sm;
  ushort* smV = sm + 8192;
  ushort* smX = sm;
  ushort* smT0 = sm + 16384;
  ushort* smT1 = sm + 24576;
  const int tid = threadIdx.x;
  const int l = tid & 63;
  const int l15 = l & 15, lg = l >> 4;
  const int w = tid >> 6;
  const int pw = w * 32;
  const int bid = blockIdx.x;
  const int role = bid >> 8;
  const int h = (bid >> 4) & 15;
  const int blk = bid & 15;
  const f32x4 zz = {0.f, 0.f, 0.f, 0.f};

  if (role == 0) {
    // ======== dQ for (h, ib = blk) ========
    // loop-invariant B-fragments (q, dO columns) live in registers
    bf16x8 bq[2][2], bo[2][2];
#pragma unroll
    for (int t = 0; t < 2; ++t)
#pragma unroll
      for (int kb = 0; kb < 2; ++kb) {
        const size_t row = (size_t)(blk * BLK + pw + 16 * t + l15) * DMODEL + h * DKD + kb * 32 + lg * 8;
        bq[t][kb] = gfrag(q + row, 1.f);
        bo[t][kb] = gfrag(dOg + row, 1.f);
      }
    f32x4 accQ[2][4] = {{zz, zz, zz, zz}, {zz, zz, zz, zz}};

    for (int j = 0; j < TB; ++j) {
      if (!mask[blk * TB + j]) continue;
      stage_T<true>(smT0, smK, kk + (size_t)(j * BLK) * DMODEL + h * DKD, SCALEF, tid);
      stage_row(smV, v + (size_t)(j * BLK) * DMODEL + h * DKD, 1.f, tid);
      __syncthreads();

      // S^T / dA^T : M = c (8 frags), N = p (2 tiles/wave)
      f32x4 ST[2][8], dAT[2][8];
#pragma unroll
      for (int t = 0; t < 2; ++t)
#pragma unroll
        for (int mf = 0; mf < 8; ++mf) { ST[t][mf] = zz; dAT[t][mf] = zz; }
#pragma unroll
      for (int kb = 0; kb < 2; ++kb) {
        const int ck = kb * 32 + lg * 8;
#pragma unroll
        for (int mf = 0; mf < 8; ++mf) {
          const bf16x8 ak = frag64(smK, mf * 16 + l15, ck);
          const bf16x8 av = frag64(smV, mf * 16 + l15, ck);
          ST[0][mf] = MFMA(ak, bq[0][kb], ST[0][mf]);
          ST[1][mf] = MFMA(ak, bq[1][kb], ST[1][mf]);
          dAT[0][mf] = MFMA(av, bo[0][kb], dAT[0][mf]);
          dAT[1][mf] = MFMA(av, bo[1][kb], dAT[1][mf]);
        }
      }
      // per-p softmax over c (32 regs + lanes l^16, l^32), then dS in regs
#pragma unroll
      for (int t = 0; t < 2; ++t) {
        float mx = -1e30f;
#pragma unroll
        for (int mf = 0; mf < 8; ++mf)
#pragma unroll
          for (int r = 0; r < 4; ++r) mx = fmaxf(mx, ST[t][mf][r]);
        mx = fmaxf(mx, __shfl_xor(mx, 16));
        mx = fmaxf(mx, __shfl_xor(mx, 32));
        float ss = 0.f;
#pragma unroll
        for (int mf = 0; mf < 8; ++mf)
#pragma unroll
          for (int r = 0; r < 4; ++r) { const float e = __expf(ST[t][mf][r] - mx); ST[t][mf][r] = e; ss += e; }
        ss += __shfl_xor(ss, 16);
        ss += __shfl_xor(ss, 32);
        const float inv = 1.f / (ss + 1e-12f);
        float rd = 0.f;
#pragma unroll
        for (int mf = 0; mf < 8; ++mf)
#pragma unroll
          for (int r = 0; r < 4; ++r) { const float pn = ST[t][mf][r] * inv; ST[t][mf][r] = pn; rd += pn * dAT[t][mf][r]; }
        rd += __shfl_xor(rd, 16);
        rd += __shfl_xor(rd, 32);
#pragma unroll
        for (int mf = 0; mf < 8; ++mf)
#pragma unroll
          for (int r = 0; r < 4; ++r) dAT[t][mf][r] = ST[t][mf][r] * (dAT[t][mf][r] - rd);
      }
      __syncthreads();   // k,v reads done -> reuse region as dS
      // write dS[p][c] (c-contiguous b64 packs)
#pragma unroll
      for (int t = 0; t < 2; ++t) {
        const int p = pw + 16 * t + l15;
#pragma unroll
        for (int mf = 0; mf < 8; ++mf) {
          const ushort2 lo = pk2(dAT[t][mf][0], dAT[t][mf][1]);
          const ushort2 hi = pk2(dAT[t][mf][2], dAT[t][mf][3]);
          ushort4 u; u.x = lo.x; u.y = lo.y; u.z = hi.x; u.w = hi.y;
          *reinterpret_cast<ushort4*>(smX + ((p * 128 + mf * 16 + 4 * lg) ^ ((p & 7) << 3))) = u;
        }
      }
      __syncthreads();
      // dQ += dS @ k   (A = dS rows p, B = kT)
#pragma unroll
      for (int kc = 0; kc < 4; ++kc) {
        const int cc = kc * 32 + lg * 8;
        const bf16x8 a0 = frag128(smX, pw + l15, cc);
        const bf16x8 a1 = frag128(smX, pw + 16 + l15, cc);
#pragma unroll
        for (int nf = 0; nf < 4; ++nf) {
          const bf16x8 b = fragT2(smT0, nf * 16 + l15, cc);
          accQ[0][nf] = MFMA(a0, b, accQ[0][nf]);
          accQ[1][nf] = MFMA(a1, b, accQ[1][nf]);
        }
      }
      __syncthreads();   // dS/kT reads done before next restage
    }
#pragma unroll
    for (int t = 0; t < 2; ++t)
#pragma unroll
      for (int nf = 0; nf < 4; ++nf)
#pragma unroll
        for (int r = 0; r < 4; ++r)
          dQ[(size_t)(blk * BLK + pw + 16 * t + lg * 4 + r) * DMODEL + h * DKD + nf * 16 + l15] = accQ[t][nf][r];

  } else {
    // ======== dK, dV for (h, jb = blk) ========
    const int jb = blk;
    f32x4 accK[2][4] = {{zz, zz, zz, zz}, {zz, zz, zz, zz}};
    f32x4 accV[2][4] = {{zz, zz, zz, zz}, {zz, zz, zz, zz}};

    for (int i = 0; i < TB; ++i) {
      if (!mask[i * TB + jb]) continue;
      stage_row(smK, kk + (size_t)(jb * BLK) * DMODEL + h * DKD, SCALEF, tid);
      stage_row(smV, v + (size_t)(jb * BLK) * DMODEL + h * DKD, 1.f, tid);
      stage_T<false>(smT0, nullptr, q + (size_t)(i * BLK) * DMODEL + h * DKD, SCALEF, tid);
      stage_T<false>(smT1, nullptr, dOg + (size_t)(i * BLK) * DMODEL + h * DKD, 1.f, tid);
      // A-fragments (q rows) straight from global
      bf16x8 aq[2][2];
#pragma unroll
      for (int Mt = 0; Mt < 2; ++Mt)
#pragma unroll
        for (int kb = 0; kb < 2; ++kb)
          aq[Mt][kb] = gfrag(q + (size_t)(i * BLK + pw + 16 * Mt + l15) * DMODEL + h * DKD + kb * 32 + lg * 8, 1.f);
      __syncthreads();

      // S = q.k^T : M = p (2 tiles/wave), N = c (8 frags)
      f32x4 S[2][8];
#pragma unroll
      for (int Mt = 0; Mt < 2; ++Mt)
#pragma unroll
        for (int nf = 0; nf < 8; ++nf) S[Mt][nf] = zz;
#pragma unroll
      for (int kb = 0; kb < 2; ++kb) {
        const int ck = kb * 32 + lg * 8;
#pragma unroll
        for (int nf = 0; nf < 8; ++nf) {
          const bf16x8 bk = frag64(smK, nf * 16 + l15, ck);
          S[0][nf] = MFMA(aq[0][kb], bk, S[0][nf]);
          S[1][nf] = MFMA(aq[1][kb], bk, S[1][nf]);
        }
      }
      // softmax over c (8 regs + lanes l^1,2,4,8) -> Pn in S
#pragma unroll
      for (int Mt = 0; Mt < 2; ++Mt)
#pragma unroll
        for (int r = 0; r < 4; ++r) {
          float mx = -1e30f;
#pragma unroll
          for (int nf = 0; nf < 8; ++nf) mx = fmaxf(mx, S[Mt][nf][r]);
          mx = fmaxf(mx, __shfl_xor(mx, 1));
          mx = fmaxf(mx, __shfl_xor(mx, 2));
          mx = fmaxf(mx, __shfl_xor(mx, 4));
          mx = fmaxf(mx, __shfl_xor(mx, 8));
          float ss = 0.f;
#pragma unroll
          for (int nf = 0; nf < 8; ++nf) { const float e = __expf(S[Mt][nf][r] - mx); S[Mt][nf][r] = e; ss += e; }
          ss += __shfl_xor(ss, 1); ss += __shfl_xor(ss, 2);
          ss += __shfl_xor(ss, 4); ss += __shfl_xor(ss, 8);
          const float inv = 1.f / (ss + 1e-12f);
#pragma unroll
          for (int nf = 0; nf < 8; ++nf) S[Mt][nf][r] *= inv;
        }
      // dA = dO.v^T
      bf16x8 ao[2][2];
#pragma unroll
      for (int Mt = 0; Mt < 2; ++Mt)
#pragma unroll
        for (int kb = 0; kb < 2; ++kb)
          ao[Mt][kb] = gfrag(dOg + (size_t)(i * BLK + pw + 16 * Mt + l15) * DMODEL + h * DKD + kb * 32 + lg * 8, 1.f);
      f32x4 dA[2][8];
#pragma unroll
      for (int Mt = 0; Mt < 2; ++Mt)
#pragma unroll
        for (int nf = 0; nf < 8; ++nf) dA[Mt][nf] = zz;
#pragma unroll
      for (int kb = 0; kb < 2; ++kb) {
        const int ck = kb * 32 + lg * 8;
#pragma unroll
        for (int nf = 0; nf < 8; ++nf) {
          const bf16x8 bv = frag64(smV, nf * 16 + l15, ck);
          dA[0][nf] = MFMA(ao[0][kb], bv, dA[0][nf]);
          dA[1][nf] = MFMA(ao[1][kb], bv, dA[1][nf]);
        }
      }
      // dS = Pn * (dA - rowdot)
#pragma unroll
      for (int Mt = 0; Mt < 2; ++Mt)
#pragma unroll
        for (int r = 0; r < 4; ++r) {
          float rd = 0.f;
#pragma unroll
          for (int nf = 0; nf < 8; ++nf) rd += S[Mt][nf][r] * dA[Mt][nf][r];
          rd += __shfl_xor(rd, 1); rd += __shfl_xor(rd, 2);
          rd += __shfl_xor(rd, 4); rd += __shfl_xor(rd, 8);
#pragma unroll
          for (int nf = 0; nf < 8; ++nf) dA[Mt][nf][r] = S[Mt][nf][r] * (dA[Mt][nf][r] - rd);
        }
      __syncthreads();   // k,v reads done -> reuse region as X

      // write Pn^T [c][p] (p-contiguous b64 packs)
#pragma unroll
      for (int Mt = 0; Mt < 2; ++Mt) {
        const int p0 = pw + 16 * Mt + 4 * lg;
#pragma unroll
        for (int nf = 0; nf < 8; ++nf) {
          const int c = nf * 16 + l15;
          const ushort2 lo = pk2(S[Mt][nf][0], S[Mt][nf][1]);
          const ushort2 hi = pk2(S[Mt][nf][2], S[Mt][nf][3]);
          ushort4 u; u.x = lo.x; u.y = lo.y; u.z = hi.x; u.w = hi.y;
          *reinterpret_cast<ushort4*>(smX + ((c * 128 + p0) ^ ((c & 7) << 3))) = u;
        }
      }
      __syncthreads();
      // dV += Pn^T @ dO   (A = PnT rows c, B = dOT)
#pragma unroll
      for (int kp = 0; kp < 4; ++kp) {
        const int pp = kp * 32 + lg * 8;
        const bf16x8 a0 = frag128(smX, pw + l15, pp);
        const bf16x8 a1 = frag128(smX, pw + 16 + l15, pp);
#pragma unroll
        for (int nf = 0; nf < 4; ++nf) {
          const bf16x8 b = fragT2(smT1, nf * 16 + l15, pp);
          accV[0][nf] = MFMA(a0, b, accV[0][nf]);
          accV[1][nf] = MFMA(a1, b, accV[1][nf]);
        }
      }
      __syncthreads();
      // write dS^T over X
#pragma unroll
      for (int Mt = 0; Mt < 2; ++Mt) {
        const int p0 = pw + 16 * Mt + 4 * lg;
#pragma unroll
        for (int nf = 0; nf < 8; ++nf) {
          const int c = nf * 16 + l15;
          const ushort2 lo = pk2(dA[Mt][nf][0], dA[Mt][nf][1]);
          const ushort2 hi = pk2(dA[Mt][nf][2], dA[Mt][nf][3]);
          ushort4 u; u.x = lo.x; u.y = lo.y; u.z = hi.x; u.w = hi.y;
          *reinterpret_cast<ushort4*>(smX + ((c * 128 + p0) ^ ((c & 7) << 3))) = u;
        }
      }
      __syncthreads();
      // dK += dS^T @ q   (A = dST rows c, B = qT; q pre-scaled)
#pragma unroll
      for (int kp = 0; kp < 4; ++kp) {
        const int pp = kp * 32 + lg * 8;
        const bf16x8 a0 = frag128(smX, pw + l15, pp);
        const bf16x8 a1 = frag128(smX, pw + 16 + l15, pp);
#pragma unroll
        for (int nf = 0; nf < 4; ++nf) {
          const bf16x8 b = fragT2(smT0, nf * 16 + l15, pp);
          accK[0][nf] = MFMA(a0, b, accK[0][nf]);
          accK[1][nf] = MFMA(a1, b, accK[1][nf]);
        }
      }
      __syncthreads();   // X/qT/dOT reads done before next restage
    }
#pragma unroll
    for (int Mt = 0; Mt < 2; ++Mt)
#pragma unroll
      for (int nf = 0; nf < 4; ++nf)
#pragma unroll
        for (int r = 0; r < 4; ++r) {
          const size_t rowo = (size_t)(jb * BLK + pw + 16 * Mt + lg * 4 + r) * DMODEL + h * DKD + nf * 16 + l15;
          dK[rowo] = accK[Mt][nf][r];
          dV[rowo] = accV[Mt][nf][r];
        }
  }
}

extern "C" void kernel_launch(void* const* d_in, const int* in_sizes, int n_in,
                              void* d_out, int out_size, void* d_ws, size_t ws_size,
                              hipStream_t stream) {
  const float* q  = (const float*)d_in[0];
  const float* k  = (const float*)d_in[1];
  const float* v  = (const float*)d_in[2];
  const float* dO = (const float*)d_in[3];
  const int* mask = (const int*)d_in[4];
  float* out = (float*)d_out;
  float* dQ = out;
  float* dK = out + (size_t)2048 * DMODEL;
  float* dV = out + (size_t)2 * 2048 * DMODEL;

  bwd_all<<<2 * NHEAD * TB, 256, 0, stream>>>(q, k, v, dO, mask, dQ, dK, dV);
}

// Round 4
// 148.814 us; speedup vs baseline: 1.8717x; 1.8717x over previous
//
#include <hip/hip_runtime.h>
#include <hip/hip_bf16.h>

#define DMODEL 1024
#define NHEAD  16
#define DKD    64
#define BLK    128
#define TB     16
#define SCALEF 0.125f   // TAU / sqrt(DK)

typedef __attribute__((ext_vector_type(8))) short bf16x8;
typedef __attribute__((ext_vector_type(4))) float f32x4;

#define MFMA(A, B, C) __builtin_amdgcn_mfma_f32_16x16x32_bf16(A, B, C, 0, 0, 0)

union U8 { bf16x8 v; ushort u[8]; ushort2 u2[4]; ushort4 u4[2]; };

__device__ __forceinline__ ushort2 pk2(float a, float b) {
  union { __hip_bfloat162 h; ushort2 u; } c;
  c.h = __float22bfloat162_rn(make_float2(a, b));
  return c.u;
}

// ---- LDS tile readers (all layouts proven in R2/R3) ----------------------
// row tile [128][64], XOR-swizzled by ((r&7)<<3)
__device__ __forceinline__ bf16x8 frag64(const ushort* T, int r, int c) {
  return *reinterpret_cast<const bf16x8*>(T + ((r * 64 + c) ^ ((r & 7) << 3)));
}
// [128][128] tile, same swizzle
__device__ __forceinline__ bf16x8 frag128(const ushort* T, int r, int c) {
  return *reinterpret_cast<const bf16x8*>(T + ((r * 128 + c) ^ ((r & 7) << 3)));
}
// chunked transposed tile: element (d, r) at (r>>2)*256 + d*4 + (r&3); r0%4==0
__device__ __forceinline__ bf16x8 fragT2(const ushort* T, int d, int r0) {
  U8 x;
  x.u4[0] = *reinterpret_cast<const ushort4*>(T + (r0 >> 2) * 256 + d * 4);
  x.u4[1] = *reinterpret_cast<const ushort4*>(T + (r0 >> 2) * 256 + 256 + d * 4);
  return x.v;
}
// global row-major -> register fragment (8 consecutive fp32)
__device__ __forceinline__ bf16x8 gfrag(const float* __restrict__ g, float sc) {
  const float4 fa = *reinterpret_cast<const float4*>(g);
  const float4 fb = *reinterpret_cast<const float4*>(g + 4);
  U8 x;
  x.u2[0] = pk2(fa.x * sc, fa.y * sc);
  x.u2[1] = pk2(fa.z * sc, fa.w * sc);
  x.u2[2] = pk2(fb.x * sc, fb.y * sc);
  x.u2[3] = pk2(fb.z * sc, fb.w * sc);
  return x.v;
}

// ---- staging: issue (global->regs) and write (regs->LDS), 512 threads ----
__device__ __forceinline__ void issue4(const float* __restrict__ g, int tid, float4* f) {
#pragma unroll
  for (int it = 0; it < 4; ++it) {
    const int idx = tid + 512 * it;
    f[it] = *reinterpret_cast<const float4*>(g + (idx >> 4) * DMODEL + 4 * (idx & 15));
  }
}
__device__ __forceinline__ void wrow(ushort* T, const float4* f, float sc, int tid) {
#pragma unroll
  for (int it = 0; it < 4; ++it) {
    const int idx = tid + 512 * it;
    const int r = idx >> 4, d4 = idx & 15;
    const ushort2 lo = pk2(f[it].x * sc, f[it].y * sc);
    const ushort2 hi = pk2(f[it].z * sc, f[it].w * sc);
    ushort4 u; u.x = lo.x; u.y = lo.y; u.z = hi.x; u.w = hi.y;
    *reinterpret_cast<ushort4*>(T + ((r * 64 + 4 * d4) ^ ((r & 7) << 3))) = u;
  }
}
// 4x4 shfl butterfly transpose (R3-proven) -> chunked T tile
__device__ __forceinline__ void wchunk(ushort* T, const float4* f, float sc, int tid) {
  const int a = (tid >> 4) & 3;
#pragma unroll
  for (int it = 0; it < 4; ++it) {
    const int idx = tid + 512 * it;
    const int r = idx >> 4, d4 = idx & 15;
    const float w0 = f[it].x * sc, w1 = f[it].y * sc, w2 = f[it].z * sc, w3 = f[it].w * sc;
    const float s0 = __shfl_xor(w1, 16), s1 = __shfl_xor(w0, 16);
    const float s2 = __shfl_xor(w3, 16), s3 = __shfl_xor(w2, 16);
    const float u0 = (a & 1) ? s0 : w0;
    const float u1 = (a & 1) ? w1 : s1;
    const float u2 = (a & 1) ? s2 : w2;
    const float u3 = (a & 1) ? w3 : s3;
    const float t0 = __shfl_xor(u2, 32), t1 = __shfl_xor(u3, 32);
    const float t2 = __shfl_xor(u0, 32), t3 = __shfl_xor(u1, 32);
    const float z0 = (a & 2) ? t0 : u0;
    const float z1 = (a & 2) ? t1 : u1;
    const float z2 = (a & 2) ? u2 : t2;
    const float z3 = (a & 2) ? u3 : t3;
    const int d = 4 * d4 + a, R0 = r - a;   // lane holds rows R0..R0+3 of col d
    const ushort2 lo = pk2(z0, z1);
    const ushort2 hi = pk2(z2, z3);
    ushort4 o; o.x = lo.x; o.y = lo.y; o.z = hi.x; o.w = hi.y;
    *reinterpret_cast<ushort4*>(T + (R0 >> 2) * 256 + d * 4) = o;
  }
}

// LDS map (ushort units), 128 KB total:
// role 0: buf0 {kR=0, vR=8192, kTc=16384}, buf1 {24576, 32768, 40960}, X=49152
// role 1: kR=0, vR=8192, qTc=16384, dOTc=24576, X1=32768, X2=49152
__global__ void __launch_bounds__(512, 1)
bwd_all(const float* __restrict__ q, const float* __restrict__ kk,
        const float* __restrict__ v, const float* __restrict__ dOg,
        const int* __restrict__ mask,
        float* __restrict__ dQ, float* __restrict__ dK, float* __restrict__ dV) {
  __shared__ ushort sm[65536];
  const int tid = threadIdx.x;
  const int l = tid & 63;
  const int l15 = l & 15, lg = l >> 4;
  const int w = tid >> 6;
  const int pw = w * 16;
  const int bid = blockIdx.x;
  // XCD-locality decode: h low 3 bits = bid&7 so each XCD sees only 2 heads
  const int h = (bid & 7) + 8 * ((bid >> 3) & 1);
  const int role = (bid >> 4) & 1;
  const int blk = bid >> 5;
  const f32x4 zz = {0.f, 0.f, 0.f, 0.f};

  if (role == 0) {
    // ================= dQ for (h, ib = blk) =================
    unsigned bm = 0;
    for (int t = 0; t < TB; ++t) bm |= mask[blk * TB + t] ? (1u << t) : 0u;
    // loop-invariant B-fragments (q, dO) in registers
    bf16x8 bq[2], bo[2];
#pragma unroll
    for (int kb = 0; kb < 2; ++kb) {
      const size_t row = (size_t)(blk * BLK + pw + l15) * DMODEL + h * DKD + kb * 32 + lg * 8;
      bq[kb] = gfrag(q + row, 1.f);
      bo[kb] = gfrag(dOg + row, 1.f);
    }
    f32x4 accQ[4] = {zz, zz, zz, zz};

    int jc = bm ? (__ffs(bm) - 1) : -1;
    unsigned rest = bm ? (bm & (bm - 1)) : 0u;
    float4 kf[4], vf[4];
    if (jc >= 0) {
      issue4(kk + (size_t)(jc * BLK) * DMODEL + h * DKD, tid, kf);
      issue4(v + (size_t)(jc * BLK) * DMODEL + h * DKD, tid, vf);
      wrow(sm + 0, kf, SCALEF, tid);
      wchunk(sm + 16384, kf, SCALEF, tid);
      wrow(sm + 8192, vf, 1.f, tid);
    }
    __syncthreads();
    int cur = 0;
    while (jc >= 0) {
      const int jn = rest ? (__ffs(rest) - 1) : -1;
      rest = rest ? (rest & (rest - 1)) : 0u;
      if (jn >= 0) {
        issue4(kk + (size_t)(jn * BLK) * DMODEL + h * DKD, tid, kf);
        issue4(v + (size_t)(jn * BLK) * DMODEL + h * DKD, tid, vf);
      }
      const ushort* kR = sm + cur * 24576;
      const ushort* vR = sm + cur * 24576 + 8192;
      const ushort* kT = sm + cur * 24576 + 16384;
      ushort* X = sm + 49152;

      // S^T = k.q^T, dA^T = v.dO^T ; lane: p = pw+l15, c = mf*16+lg*4+r
      f32x4 ST[8], dAT[8];
#pragma unroll
      for (int mf = 0; mf < 8; ++mf) { ST[mf] = zz; dAT[mf] = zz; }
#pragma unroll
      for (int kb = 0; kb < 2; ++kb) {
        const int ck = kb * 32 + lg * 8;
#pragma unroll
        for (int mf = 0; mf < 8; ++mf) {
          ST[mf]  = MFMA(frag64(kR, mf * 16 + l15, ck), bq[kb], ST[mf]);
          dAT[mf] = MFMA(frag64(vR, mf * 16 + l15, ck), bo[kb], dAT[mf]);
        }
      }
      // per-p softmax over 128 c (regs + lanes l^16, l^32)
      float mx = -1e30f;
#pragma unroll
      for (int mf = 0; mf < 8; ++mf)
#pragma unroll
        for (int r = 0; r < 4; ++r) mx = fmaxf(mx, ST[mf][r]);
      mx = fmaxf(mx, __shfl_xor(mx, 16));
      mx = fmaxf(mx, __shfl_xor(mx, 32));
      float ss = 0.f;
#pragma unroll
      for (int mf = 0; mf < 8; ++mf)
#pragma unroll
        for (int r = 0; r < 4; ++r) { const float e = __expf(ST[mf][r] - mx); ST[mf][r] = e; ss += e; }
      ss += __shfl_xor(ss, 16);
      ss += __shfl_xor(ss, 32);
      const float inv = 1.f / (ss + 1e-12f);
      float rd = 0.f;
#pragma unroll
      for (int mf = 0; mf < 8; ++mf)
#pragma unroll
        for (int r = 0; r < 4; ++r) { const float pn = ST[mf][r] * inv; ST[mf][r] = pn; rd += pn * dAT[mf][r]; }
      rd += __shfl_xor(rd, 16);
      rd += __shfl_xor(rd, 32);
#pragma unroll
      for (int mf = 0; mf < 8; ++mf)
#pragma unroll
        for (int r = 0; r < 4; ++r) dAT[mf][r] = ST[mf][r] * (dAT[mf][r] - rd);

      // write dS[p][c] into X (b64 packs)
      const int p = pw + l15;
#pragma unroll
      for (int mf = 0; mf < 8; ++mf) {
        const ushort2 lo = pk2(dAT[mf][0], dAT[mf][1]);
        const ushort2 hi = pk2(dAT[mf][2], dAT[mf][3]);
        ushort4 u; u.x = lo.x; u.y = lo.y; u.z = hi.x; u.w = hi.y;
        *reinterpret_cast<ushort4*>(X + ((p * 128 + mf * 16 + 4 * lg) ^ ((p & 7) << 3))) = u;
      }
      __syncthreads();   // [B1] X visible; all S-phase reads of buf[cur] done

      // dQ += dS @ k  (A = dS rows p from X, B = kT chunked)
#pragma unroll
      for (int kc = 0; kc < 4; ++kc) {
        const int cc = kc * 32 + lg * 8;
        const bf16x8 a = frag128(X, pw + l15, cc);
#pragma unroll
        for (int nf = 0; nf < 4; ++nf)
          accQ[nf] = MFMA(a, fragT2(kT, nf * 16 + l15, cc), accQ[nf]);
      }
      if (jn >= 0) {
        ushort* nb = sm + (cur ^ 1) * 24576;
        wrow(nb, kf, SCALEF, tid);
        wchunk(nb + 16384, kf, SCALEF, tid);
        wrow(nb + 8192, vf, 1.f, tid);
      }
      __syncthreads();   // [B2] next buf visible; X safe to rewrite
      cur ^= 1;
      jc = jn;
    }
#pragma unroll
    for (int nf = 0; nf < 4; ++nf)
#pragma unroll
      for (int r = 0; r < 4; ++r)
        dQ[(size_t)(blk * BLK + pw + lg * 4 + r) * DMODEL + h * DKD + nf * 16 + l15] = accQ[nf][r];

  } else {
    // ================= dK, dV for (h, jb = blk) =================
    const int jb = blk;
    unsigned bm = 0;
    for (int t = 0; t < TB; ++t) bm |= mask[t * TB + jb] ? (1u << t) : 0u;
    ushort* kR = sm;
    ushort* vR = sm + 8192;
    ushort* qT = sm + 16384;
    ushort* oT = sm + 24576;
    ushort* X1 = sm + 32768;
    ushort* X2 = sm + 49152;

    f32x4 accK[4] = {zz, zz, zz, zz};
    f32x4 accV[4] = {zz, zz, zz, zz};

    int ic = bm ? (__ffs(bm) - 1) : -1;
    unsigned rest = bm ? (bm & (bm - 1)) : 0u;
    {
      float4 tf[4];
      issue4(kk + (size_t)(jb * BLK) * DMODEL + h * DKD, tid, tf);
      wrow(kR, tf, SCALEF, tid);
      issue4(v + (size_t)(jb * BLK) * DMODEL + h * DKD, tid, tf);
      wrow(vR, tf, 1.f, tid);
      if (ic >= 0) {
        issue4(q + (size_t)(ic * BLK) * DMODEL + h * DKD, tid, tf);
        wchunk(qT, tf, SCALEF, tid);
        issue4(dOg + (size_t)(ic * BLK) * DMODEL + h * DKD, tid, tf);
        wchunk(oT, tf, 1.f, tid);
      }
    }
    __syncthreads();

    float4 qf[4], of[4];
    while (ic >= 0) {
      const int in = rest ? (__ffs(rest) - 1) : -1;
      rest = rest ? (rest & (rest - 1)) : 0u;
      // A-fragments for current i straight from global (L2-hot: just staged)
      bf16x8 aq[2], ao[2];
#pragma unroll
      for (int kb = 0; kb < 2; ++kb) {
        const size_t row = (size_t)(ic * BLK + pw + l15) * DMODEL + h * DKD + kb * 32 + lg * 8;
        aq[kb] = gfrag(q + row, 1.f);
        ao[kb] = gfrag(dOg + row, 1.f);
      }
      if (in >= 0) {
        issue4(q + (size_t)(in * BLK) * DMODEL + h * DKD, tid, qf);
        issue4(dOg + (size_t)(in * BLK) * DMODEL + h * DKD, tid, of);
      }

      // S = q.k^T, dA = dO.v^T ; lane: p = pw+lg*4+r, c = nf*16+l15
      f32x4 S[8], dA[8];
#pragma unroll
      for (int nf = 0; nf < 8; ++nf) { S[nf] = zz; dA[nf] = zz; }
#pragma unroll
      for (int kb = 0; kb < 2; ++kb) {
        const int ck = kb * 32 + lg * 8;
#pragma unroll
        for (int nf = 0; nf < 8; ++nf) {
          S[nf]  = MFMA(aq[kb], frag64(kR, nf * 16 + l15, ck), S[nf]);
          dA[nf] = MFMA(ao[kb], frag64(vR, nf * 16 + l15, ck), dA[nf]);
        }
      }
      // softmax over c per row; then dS = Pn*(dA - rowdot)
#pragma unroll
      for (int r = 0; r < 4; ++r) {
        float mx = -1e30f;
#pragma unroll
        for (int nf = 0; nf < 8; ++nf) mx = fmaxf(mx, S[nf][r]);
        mx = fmaxf(mx, __shfl_xor(mx, 1));
        mx = fmaxf(mx, __shfl_xor(mx, 2));
        mx = fmaxf(mx, __shfl_xor(mx, 4));
        mx = fmaxf(mx, __shfl_xor(mx, 8));
        float ss = 0.f;
#pragma unroll
        for (int nf = 0; nf < 8; ++nf) { const float e = __expf(S[nf][r] - mx); S[nf][r] = e; ss += e; }
        ss += __shfl_xor(ss, 1); ss += __shfl_xor(ss, 2);
        ss += __shfl_xor(ss, 4); ss += __shfl_xor(ss, 8);
        const float inv = 1.f / (ss + 1e-12f);
        float rd = 0.f;
#pragma unroll
        for (int nf = 0; nf < 8; ++nf) { const float pn = S[nf][r] * inv; S[nf][r] = pn; rd += pn * dA[nf][r]; }
        rd += __shfl_xor(rd, 1); rd += __shfl_xor(rd, 2);
        rd += __shfl_xor(rd, 4); rd += __shfl_xor(rd, 8);
#pragma unroll
        for (int nf = 0; nf < 8; ++nf) dA[nf][r] = S[nf][r] * (dA[nf][r] - rd);
      }
      // write PnT -> X1 and dST -> X2 ([c][p], b64 packs)
#pragma unroll
      for (int nf = 0; nf < 8; ++nf) {
        const int c = nf * 16 + l15;
        const int off = (c * 128 + pw + 4 * lg) ^ ((c & 7) << 3);
        {
          const ushort2 lo = pk2(S[nf][0], S[nf][1]);
          const ushort2 hi = pk2(S[nf][2], S[nf][3]);
          ushort4 u; u.x = lo.x; u.y = lo.y; u.z = hi.x; u.w = hi.y;
          *reinterpret_cast<ushort4*>(X1 + off) = u;
        }
        {
          const ushort2 lo = pk2(dA[nf][0], dA[nf][1]);
          const ushort2 hi = pk2(dA[nf][2], dA[nf][3]);
          ushort4 u; u.x = lo.x; u.y = lo.y; u.z = hi.x; u.w = hi.y;
          *reinterpret_cast<ushort4*>(X2 + off) = u;
        }
      }
      __syncthreads();   // [B] X1/X2 visible

      // dV += Pn^T @ dO ; dK += dS^T @ q   (wave owns c-slice pw..pw+15)
#pragma unroll
      for (int kp = 0; kp < 4; ++kp) {
        const int pp = kp * 32 + lg * 8;
        const bf16x8 a1 = frag128(X1, pw + l15, pp);
        const bf16x8 a2 = frag128(X2, pw + l15, pp);
#pragma unroll
        for (int nf = 0; nf < 4; ++nf) {
          accV[nf] = MFMA(a1, fragT2(oT, nf * 16 + l15, pp), accV[nf]);
          accK[nf] = MFMA(a2, fragT2(qT, nf * 16 + l15, pp), accK[nf]);
        }
      }
      __syncthreads();   // [C] all reads of qT/oT/X done
      if (in >= 0) {
        wchunk(qT, qf, SCALEF, tid);
        wchunk(oT, of, 1.f, tid);
      }
      __syncthreads();   // [D] staged tiles visible
      ic = in;
    }
#pragma unroll
    for (int nf = 0; nf < 4; ++nf)
#pragma unroll
      for (int r = 0; r < 4; ++r) {
        const size_t rowo = (size_t)(jb * BLK + pw + lg * 4 + r) * DMODEL + h * DKD + nf * 16 + l15;
        dK[rowo] = accK[nf][r];
        dV[rowo] = accV[nf][r];
      }
  }
}

extern "C" void kernel_launch(void* const* d_in, const int* in_sizes, int n_in,
                              void* d_out, int out_size, void* d_ws, size_t ws_size,
                              hipStream_t stream) {
  const float* q  = (const float*)d_in[0];
  const float* k  = (const float*)d_in[1];
  const float* v  = (const float*)d_in[2];
  const float* dO = (const float*)d_in[3];
  const int* mask = (const int*)d_in[4];
  float* out = (float*)d_out;
  float* dQ = out;
  float* dK = out + (size_t)2048 * DMODEL;
  float* dV = out + (size_t)2 * 2048 * DMODEL;

  bwd_all<<<2 * NHEAD * TB, 512, 0, stream>>>(q, k, v, dO, mask, dQ, dK, dV);
}